// Round 8
// baseline (198.298 us; speedup 1.0000x reference)
//
#include <hip/hip_runtime.h>
#include <math.h>

// Problem constants
#define BATCH 256
#define IC    1152
#define EDIM  8
#define NC    10
#define DV    16

// Tiling
#define ITILE  8                    // i's covered by thread layout (il = 0..7)
#define NCHUNK 2                    // i-chunks looped per block
#define ITOT   (ITILE * NCHUNK)     // 16 i's per block
#define NB     4                    // b's per block (register s-acc = 20 VGPRs)
#define NTHREADS 256                // 8 il * 2 ch * 16 d
#define NWAVES 4
#define NSLAB  (IC / ITOT)          // 72 partial slabs (= 9 * 8 for XCD swizzle)
#define BCHUNKS (BATCH / NB)        // 64
#define SCD (NC * DV)               // 160
#define SPART_STRIDE (BATCH * SCD)  // 40960 floats per slab

// ---------------------------------------------------------------------------
// DPP-based 16-lane (row) sum reduce — all VALU, no DS pipe. HW-verified.
// ---------------------------------------------------------------------------
template<int CTRL>
__device__ __forceinline__ float dpp_add(float x) {
    int r = __builtin_amdgcn_update_dpp(0, __float_as_int(x), CTRL, 0xF, 0xF, true);
    return x + __int_as_float(r);
}
__device__ __forceinline__ float row_reduce16(float x) {
    x = dpp_add<0xB1>(x);   // quad_perm [1,0,3,2] : xor 1
    x = dpp_add<0x4E>(x);   // quad_perm [2,3,0,1] : xor 2
    x = dpp_add<0x141>(x);  // row_half_mirror     : xor 4
    x = dpp_add<0x140>(x);  // row_mirror          : xor 8
    return x;
}

// ---------------------------------------------------------------------------
// Main fused kernel. tid = il*32 + ch*16 + d.
//
// XCD-AWARE SWIZZLE (R8): R7 showed mains mode-invariant at 60 us with ~377 MB
// of W L2->CU traffic per dispatch; W (5.9 MB) doesn't fit a 4 MB per-XCD L2
// when every XCD sees every icb. 1-D grid, bid%8 = XCD round-robin key ->
// each XCD owns a contiguous 9-icb slice (738 KB of W, L2-resident).
//
// SPILL HISTORY (do not regress): NB=8 needs ~130 live VGPRs -> allocator
// spills at every boundary (R4/R5/R6). NB=4 (~110 live) + bounds (256,2).
//
// In-loop globals: W ONLY. v and b2 are staged to LDS at block start.
// Softmax has NO max-subtraction: logits are bounded (|b| < ~50 << 88) so
// exp() cannot overflow in fp32; identical result, one less DS dependency.
//
// MODE 1: c = softmax(bias)                       -> s1 partials
// MODE 2: b2 = (u.v1) + 2*bias (stored), softmax  -> s2 partials
// MODE 3: b3 = (u.v2) + b2 + bias, softmax        -> s3 partials
// ---------------------------------------------------------------------------
template<int MODE>
__global__ __launch_bounds__(NTHREADS, 2)
void caps_main(const float* __restrict__ x,
               const float* __restrict__ W,
               const float* __restrict__ bias,
               const float* __restrict__ v_in,
               float* __restrict__ b2,
               float* __restrict__ s_part)
{
    __shared__ float sx[NB][ITOT * EDIM];    // 2 KB
    __shared__ float sv[NB][SCD];            // 2.5 KB (MODE != 1)
    __shared__ float sb2[NB][ITOT * 16];     // 4 KB  (MODE == 3) [b][i][ch*8+k]
    __shared__ float swv[NWAVES][NB][SCD];   // 10 KB — wave-private slabs

    const int tid = threadIdx.x;
    const int d   = tid & 15;
    const int ch  = (tid >> 4) & 1;
    const int il  = tid >> 5;                // 0..7
    const int wid = tid >> 6;                // 0..3

    const int bid = blockIdx.x;              // 0..4607
    const int xcd = bid & 7;                 // XCD round-robin key
    const int grp = bid >> 3;                // 0..575
    const int icb = xcd * 9 + (grp % 9);     // 0..71  (contiguous slice per XCD)
    const int bcb = grp / 9;                 // 0..63
    const int i0  = icb * ITOT;
    const int b0  = bcb * NB;

    // ---- stage x slice: 128 float4, coalesced ----
    if (tid < NB * ITOT * EDIM / 4) {
        const float4* xg = (const float4*)x;
        int bb = tid >> 5;                   // 32 float4 per b row
        int w  = tid & 31;
        ((float4*)&sx[0][0])[tid] =
            xg[(size_t)(b0 + bb) * (IC * EDIM / 4) + i0 * (EDIM / 4) + w];
    }
    if (MODE != 1) {
        // v rows b0..b0+3 are contiguous: 640 floats = 160 float4
        if (tid < NB * SCD / 4)
            ((float4*)&sv[0][0])[tid] =
                ((const float4*)v_in)[(size_t)b0 * (SCD / 4) + tid];
    }
    if (MODE == 3) {
        // b2 padded [b][i][ch][8]: per b, 256 contiguous floats at (b*IC+i0)*16
        const float4* bg = (const float4*)b2;
        int bb = tid >> 6;                   // 64 float4 per b
        int w  = tid & 63;
        ((float4*)&sb2[0][0])[tid] = bg[((size_t)(b0 + bb) * IC + i0) * 4 + w];
    }

    float sacc[NB][5];
    #pragma unroll
    for (int bb = 0; bb < NB; ++bb)
        #pragma unroll
        for (int k = 0; k < 5; ++k) sacc[bb][k] = 0.f;

    __syncthreads();

    const float4* Wg = (const float4*)W;

    #pragma unroll 1
    for (int icl = 0; icl < NCHUNK; ++icl) {
        const int i = i0 + icl * ITILE + il;

        // W fragment + bias for this i-chunk (the ONLY in-loop global loads)
        float4 w4[5][2];
        float  bv[5];
        #pragma unroll
        for (int k = 0; k < 5; ++k) {
            int c = ch * 5 + k;
            size_t base = ((size_t)(i * NC + c) * DV + d) * 2;
            w4[k][0] = Wg[base];
            w4[k][1] = Wg[base + 1];
            bv[k]    = bias[i * NC + c];
        }

        float cw[5];
        if (MODE == 1) {
            // softmax(bias[i,:]) — batch-independent; no max-subtraction
            float ssum = 0.f, ex[5];
            #pragma unroll
            for (int k = 0; k < 5; ++k) { ex[k] = __expf(bv[k]); ssum += ex[k]; }
            ssum += __shfl_xor(ssum, 16);
            float inv = 1.0f / ssum;
            #pragma unroll
            for (int k = 0; k < 5; ++k) cw[k] = ex[k] * inv;
        }

        #pragma unroll
        for (int bb = 0; bb < NB; ++bb) {
            const float4 x0 = ((const float4*)&sx[bb][(icl * ITILE + il) * EDIM])[0];
            const float4 x1 = ((const float4*)&sx[bb][(icl * ITILE + il) * EDIM])[1];

            // u_hat[b, i, c_k, d]
            float u[5];
            #pragma unroll
            for (int k = 0; k < 5; ++k) {
                float acc = w4[k][0].x * x0.x;
                acc = fmaf(w4[k][0].y, x0.y, acc);
                acc = fmaf(w4[k][0].z, x0.z, acc);
                acc = fmaf(w4[k][0].w, x0.w, acc);
                acc = fmaf(w4[k][1].x, x1.x, acc);
                acc = fmaf(w4[k][1].y, x1.y, acc);
                acc = fmaf(w4[k][1].z, x1.z, acc);
                acc = fmaf(w4[k][1].w, x1.w, acc);
                u[k] = acc;
            }

            if (MODE != 1) {
                // agreement: sum over d via DPP; v from LDS (broadcast reads)
                float t[5];
                #pragma unroll
                for (int k = 0; k < 5; ++k)
                    t[k] = u[k] * sv[bb][ch * 80 + k * 16 + d];
                #pragma unroll
                for (int k = 0; k < 5; ++k) t[k] = row_reduce16(t[k]);

                float br[5];
                if (MODE == 2) {
                    #pragma unroll
                    for (int k = 0; k < 5; ++k) br[k] = t[k] + 2.0f * bv[k];
                    if (d == 0) {
                        float* bp = b2 + (((size_t)(b0 + bb) * IC + i) * 2 + ch) * 8;
                        #pragma unroll
                        for (int k = 0; k < 5; ++k) bp[k] = br[k];
                    }
                } else {
                    const float* bp = &sb2[bb][(icl * ITILE + il) * 16 + ch * 8];
                    #pragma unroll
                    for (int k = 0; k < 5; ++k) br[k] = t[k] + bp[k] + bv[k];
                }
                // softmax over 10 c's (5 local + partner half); no max needed:
                // logits bounded (|agr| <= ||u||*||v|| ~ few, bias ~0) << 88
                float ssum = 0.f, ex[5];
                #pragma unroll
                for (int k = 0; k < 5; ++k) { ex[k] = __expf(br[k]); ssum += ex[k]; }
                ssum += __shfl_xor(ssum, 16);
                float inv = 1.0f / ssum;
                #pragma unroll
                for (int k = 0; k < 5; ++k) cw[k] = ex[k] * inv;
            }

            // register s-accumulation
            #pragma unroll
            for (int k = 0; k < 5; ++k)
                sacc[bb][k] = fmaf(cw[k], u[k], sacc[bb][k]);
        }
    }

    // ---- epilogue: i-pair reduce + wave slabs + 4-way reduce + flush ----
    #pragma unroll
    for (int bb = 0; bb < NB; ++bb) {
        #pragma unroll
        for (int k = 0; k < 5; ++k) {
            float s = sacc[bb][k] + __shfl_xor(sacc[bb][k], 32);
            if ((tid & 32) == 0)
                swv[wid][bb][ch * 80 + k * 16 + d] = s;
        }
    }
    __syncthreads();
    for (int j = tid; j < NB * SCD; j += NTHREADS) {    // 640 elems
        int bb = j / SCD;
        int cd = j - bb * SCD;
        float s = (swv[0][bb][cd] + swv[1][bb][cd])
                + (swv[2][bb][cd] + swv[3][bb][cd]);
        s_part[((size_t)icb * BATCH + b0 + bb) * SCD + cd] = s;
    }
}

// ---------------------------------------------------------------------------
// Reduce s-partials over the 72 slabs and apply squash.
// Block = 16 (b,c) groups x 16 d. Grid = 2560/16 = 160 blocks.
// ---------------------------------------------------------------------------
__global__ __launch_bounds__(256)
void caps_squash(const float* __restrict__ s_part, float* __restrict__ out)
{
    const int tid = threadIdx.x;
    const int bc  = blockIdx.x * 16 + (tid >> 4);
    const size_t off = (size_t)bc * DV + (tid & 15);

    float a[8] = {0.f, 0.f, 0.f, 0.f, 0.f, 0.f, 0.f, 0.f};
    #pragma unroll
    for (int ic = 0; ic < NSLAB; ic += 8) {
        #pragma unroll
        for (int j = 0; j < 8; ++j)
            a[j] += s_part[(size_t)(ic + j) * SPART_STRIDE + off];
    }
    float s = ((a[0] + a[1]) + (a[2] + a[3])) + ((a[4] + a[5]) + (a[6] + a[7]));

    float sq = row_reduce16(s * s);

    // scale = sq/(1+sq)/sqrt(sq+EPS), EPS = 1e-7 (matches reference)
    float scale = sq / ((1.0f + sq) * sqrtf(sq + 1e-7f));
    out[off] = scale * s;
}

// ---------------------------------------------------------------------------
extern "C" void kernel_launch(void* const* d_in, const int* in_sizes, int n_in,
                              void* d_out, int out_size, void* d_ws, size_t ws_size,
                              hipStream_t stream)
{
    const float* x    = (const float*)d_in[0];   // [256,1152,8]
    const float* W    = (const float*)d_in[1];   // [1152,10,16,8]
    const float* bias = (const float*)d_in[2];   // [1152,10]
    float* out = (float*)d_out;                  // [256,10,16]

    float* ws     = (float*)d_ws;
    float* s_part = ws;                                       // 72*40960 = 2,949,120 f
    float* v      = s_part + (size_t)NSLAB * SPART_STRIDE;    // 40,960 f
    float* b2     = v + SPART_STRIDE;                         // padded: 4,718,592 f
    // total ws use: ~31 MB (< 35.5 MB proven in R1)

    const int grid = NSLAB * BCHUNKS;   // 72 * 64 = 4608 blocks (1-D, XCD swizzled)

    // iter 1
    caps_main<1><<<grid, NTHREADS, 0, stream>>>(x, W, bias, v, b2, s_part);
    caps_squash<<<160, 256, 0, stream>>>(s_part, v);
    // iter 2
    caps_main<2><<<grid, NTHREADS, 0, stream>>>(x, W, bias, v, b2, s_part);
    caps_squash<<<160, 256, 0, stream>>>(s_part, v);
    // final
    caps_main<3><<<grid, NTHREADS, 0, stream>>>(x, W, bias, v, b2, s_part);
    caps_squash<<<160, 256, 0, stream>>>(s_part, out);
}